// Round 6
// baseline (259.243 us; speedup 1.0000x reference)
//
#include <hip/hip_runtime.h>

#define DEV __device__ __forceinline__

constexpr int B_  = 4;
constexpr int C_  = 256;
constexpr int C8_ = 32;
constexpr int N_  = 4096;   // 64*64

using u16 = unsigned short;
using u32 = unsigned int;

typedef __attribute__((ext_vector_type(8))) short bf16x8;
typedef __attribute__((ext_vector_type(4))) float f32x4;

DEV float bf2f(u16 u) { return __uint_as_float(((u32)u) << 16); }
DEV u16   f2bf(float f) {
  u32 i = __float_as_uint(f);
  i += 0x7fffu + ((i >> 16) & 1u);   // round-to-nearest-even
  return (u16)(i >> 16);
}

// ---------------------------------------------------------------------------
// Split all four weight matrices into hi/lo bf16 tables (one-time prep).
// total elems: Wq 8192 + Wk 8192 + Wv 65536 + Wo 65536 = 147456 = 576*256
// ---------------------------------------------------------------------------
__global__ __launch_bounds__(256) void wsplit(
    const float* __restrict__ Wq, const float* __restrict__ Wk,
    const float* __restrict__ Wv, const float* __restrict__ Wo,
    u16* __restrict__ WqH, u16* __restrict__ WqL,
    u16* __restrict__ WkH, u16* __restrict__ WkL,
    u16* __restrict__ WvH, u16* __restrict__ WvL,
    u16* __restrict__ WoH, u16* __restrict__ WoL)
{
  int i = blockIdx.x * 256 + threadIdx.x;
  const float* src; u16 *h, *l; int off;
  if (i < 8192)        { src = Wq; h = WqH; l = WqL; off = i; }
  else if (i < 16384)  { src = Wk; h = WkH; l = WkL; off = i - 8192; }
  else if (i < 81920)  { src = Wv; h = WvH; l = WvL; off = i - 16384; }
  else                 { src = Wo; h = WoH; l = WoL; off = i - 81920; }
  float v = src[off];
  u16 hi = f2bf(v);
  h[off] = hi;
  l[off] = f2bf(v - bf2f(hi));
}

// ---------------------------------------------------------------------------
// x (B,C,N) f32 -> xTh, xTl (B,N,C) bf16 hi/lo (transpose via LDS).
// grid (N/64, C/64, B), block 256.
// ---------------------------------------------------------------------------
__global__ __launch_bounds__(256) void xprep(
    const float* __restrict__ x, u16* __restrict__ xTh, u16* __restrict__ xTl)
{
  __shared__ float tf[64][65];   // pad 65 -> conflict-free both directions
  const int tid = threadIdx.x;
  const int b = blockIdx.z, c0 = blockIdx.y * 64, n0 = blockIdx.x * 64;
  const int nl = tid & 63, cb = tid >> 6;

  #pragma unroll
  for (int cc = 0; cc < 16; ++cc) {
    int cl = cb * 16 + cc;
    tf[nl][cl] = x[((size_t)b * C_ + c0 + cl) * N_ + n0 + nl];
  }
  __syncthreads();

  #pragma unroll
  for (int it = 0; it < 2; ++it) {
    int idx = tid + it * 256;
    int n = idx >> 3, q = idx & 7;
    u32 ph[4], pl[4];
    #pragma unroll
    for (int j = 0; j < 4; ++j) {
      float v0 = tf[n][q * 8 + 2 * j], v1 = tf[n][q * 8 + 2 * j + 1];
      u16 h0 = f2bf(v0), h1 = f2bf(v1);
      ph[j] = (u32)h0 | ((u32)h1 << 16);
      pl[j] = (u32)f2bf(v0 - bf2f(h0)) | ((u32)f2bf(v1 - bf2f(h1)) << 16);
    }
    size_t off = ((size_t)b * N_ + n0 + n) * C_ + c0 + q * 8;
    *(uint4*)&xTh[off] = make_uint4(ph[0], ph[1], ph[2], ph[3]);
    *(uint4*)&xTl[off] = make_uint4(pl[0], pl[1], pl[2], pl[3]);
  }
}

// ---------------------------------------------------------------------------
// q/k/v projections, pure MFMA with direct-global fragments.
// grid (N/32, B), block 256.  wave w: v-channels [64w,64w+64); qk-tile w.
// ---------------------------------------------------------------------------
__global__ __launch_bounds__(256) void qkv_mfma(
    const u16* __restrict__ xTh, const u16* __restrict__ xTl,
    const u16* __restrict__ WqH, const u16* __restrict__ WqL,
    const u16* __restrict__ WkH, const u16* __restrict__ WkL,
    const u16* __restrict__ WvH, const u16* __restrict__ WvL,
    const float* __restrict__ bq, const float* __restrict__ bk,
    const float* __restrict__ bv,
    u16* __restrict__ qt, u16* __restrict__ kt, u16* __restrict__ vb)
{
  const int tid = threadIdx.x;
  const int lane = tid & 63, w = tid >> 6, m = lane & 15, quad = lane >> 4;
  const int b = blockIdx.y, n0 = blockIdx.x * 32;

  const u16* qkH = (w < 2) ? (WqH + (size_t)(w * 16 + m) * C_)
                           : (WkH + (size_t)((w - 2) * 16 + m) * C_);
  const u16* qkL = (w < 2) ? (WqL + (size_t)(w * 16 + m) * C_)
                           : (WkL + (size_t)((w - 2) * 16 + m) * C_);
  const size_t nr0 = (size_t)b * N_ + n0 + m;

  f32x4 ov[4][2], oq[2];
  #pragma unroll
  for (int dt = 0; dt < 4; ++dt)
    #pragma unroll
    for (int nt = 0; nt < 2; ++nt) ov[dt][nt] = (f32x4){0.f, 0.f, 0.f, 0.f};
  #pragma unroll
  for (int nt = 0; nt < 2; ++nt) oq[nt] = (f32x4){0.f, 0.f, 0.f, 0.f};

  for (int K = 0; K < 8; ++K) {
    const int ko = K * 32 + quad * 8;
    bf16x8 xh[2], xl[2];
    #pragma unroll
    for (int nt = 0; nt < 2; ++nt) {
      xh[nt] = *(const bf16x8*)(xTh + (nr0 + nt * 16) * C_ + ko);
      xl[nt] = *(const bf16x8*)(xTl + (nr0 + nt * 16) * C_ + ko);
    }
    #pragma unroll
    for (int dt = 0; dt < 4; ++dt) {
      bf16x8 whi = *(const bf16x8*)(WvH + (size_t)(64 * w + dt * 16 + m) * C_ + ko);
      bf16x8 wlo = *(const bf16x8*)(WvL + (size_t)(64 * w + dt * 16 + m) * C_ + ko);
      #pragma unroll
      for (int nt = 0; nt < 2; ++nt) {
        ov[dt][nt] = __builtin_amdgcn_mfma_f32_16x16x32_bf16(whi, xh[nt], ov[dt][nt], 0, 0, 0);
        ov[dt][nt] = __builtin_amdgcn_mfma_f32_16x16x32_bf16(whi, xl[nt], ov[dt][nt], 0, 0, 0);
        ov[dt][nt] = __builtin_amdgcn_mfma_f32_16x16x32_bf16(wlo, xh[nt], ov[dt][nt], 0, 0, 0);
      }
    }
    {
      bf16x8 bhi = *(const bf16x8*)(qkH + ko);
      bf16x8 blo = *(const bf16x8*)(qkL + ko);
      #pragma unroll
      for (int nt = 0; nt < 2; ++nt) {
        oq[nt] = __builtin_amdgcn_mfma_f32_16x16x32_bf16(xh[nt], bhi, oq[nt], 0, 0, 0);
        oq[nt] = __builtin_amdgcn_mfma_f32_16x16x32_bf16(xl[nt], bhi, oq[nt], 0, 0, 0);
        oq[nt] = __builtin_amdgcn_mfma_f32_16x16x32_bf16(xh[nt], blo, oq[nt], 0, 0, 0);
      }
    }
  }

  // v epilogue (D rows = out-channel, cols = n)
  #pragma unroll
  for (int dt = 0; dt < 4; ++dt)
    #pragma unroll
    for (int r = 0; r < 4; ++r) {
      int oc = 64 * w + dt * 16 + quad * 4 + r;
      float bias = bv[oc];
      #pragma unroll
      for (int nt = 0; nt < 2; ++nt)
        vb[((size_t)b * C_ + oc) * N_ + n0 + nt * 16 + m] = f2bf(ov[dt][nt][r] + bias);
    }
  // qk epilogue (D rows = n, cols = d)
  {
    u16* qk_out = (w < 2) ? qt : kt;
    const float* qbias = (w < 2) ? bq : bk;
    int dbase = (w & 1) * 16;
    float bias = qbias[dbase + m];
    #pragma unroll
    for (int nt = 0; nt < 2; ++nt)
      #pragma unroll
      for (int r = 0; r < 4; ++r)
        qk_out[((size_t)b * N_ + n0 + nt * 16 + quad * 4 + r) * C8_ + dbase + m] =
            f2bf(oq[nt][r] + bias);
  }
}

// ---------------------------------------------------------------------------
// MFMA flash attention, split-K=2, TJ=128, explicit K/V register pipeline.
// grid (N/64, 2, B) linearized+swizzled; block 256 (4 waves).
// ---------------------------------------------------------------------------
__global__ __launch_bounds__(256, 2) void attn_mfma(
    const u16* __restrict__ qt, const u16* __restrict__ kt,
    const u16* __restrict__ vb,
    float* __restrict__ Opart, float* __restrict__ ml)
{
  __shared__ __align__(16) u16  ps[2][64][136];
  __shared__ __align__(16) float als[2][64];

  const int tid = threadIdx.x, lane = tid & 63, w = tid >> 6;
  const int m = lane & 15, quad = lane >> 4;

  const int lid = blockIdx.x + gridDim.x * (blockIdx.y + gridDim.y * blockIdx.z);
  const int grp = lid & 7, ksl = grp & 1, b = grp >> 1;
  const int i0 = (lid >> 3) * 64;

  const bf16x8 qfrag =
      *(const bf16x8*)(qt + ((size_t)b * N_ + i0 + w * 16 + m) * C8_ + quad * 8);
  const u16* kbase = kt + (size_t)b * N_ * C8_;
  const u16* vrow  = vb + ((size_t)b * C_ + w * 64 + m) * N_;

  f32x4 o[4][4];
  #pragma unroll
  for (int t = 0; t < 4; ++t)
    #pragma unroll
    for (int ct = 0; ct < 4; ++ct) o[t][ct] = (f32x4){0.f, 0.f, 0.f, 0.f};
  float m_r = -1e30f, l_r = 0.f;

  const int jbeg = ksl * 2048, jend = jbeg + 2048;
  int buf = 0;

  // loop-carried pipeline registers: K tile + first half of V tile
  bf16x8 kA[8], vB01[2][4], vB23[2][4];
  #pragma unroll
  for (int t = 0; t < 8; ++t)
    kA[t] = *(const bf16x8*)(kbase + (size_t)(jbeg + t * 16 + m) * C8_ + quad * 8);
  #pragma unroll
  for (int ct = 0; ct < 2; ++ct)
    #pragma unroll
    for (int kk = 0; kk < 4; ++kk)
      vB01[ct][kk] = *(const bf16x8*)(vrow + (size_t)ct * 16 * N_ + jbeg + kk * 32 + quad * 8);

  for (int j0 = jbeg; j0 < jend; j0 += 128, buf ^= 1) {
    // second half of current V tile: issued now, consumed at PV (far below)
    #pragma unroll
    for (int ct = 0; ct < 2; ++ct)
      #pragma unroll
      for (int kk = 0; kk < 4; ++kk)
        vB23[ct][kk] = *(const bf16x8*)(vrow + (size_t)(ct + 2) * 16 * N_ + j0 + kk * 32 + quad * 8);

    // S^T: kA already resident (prefetched last iter) -> no load stall
    f32x4 s[8];
    #pragma unroll
    for (int t = 0; t < 8; ++t)
      s[t] = __builtin_amdgcn_mfma_f32_16x16x32_bf16(
          kA[t], qfrag, (f32x4){0.f, 0.f, 0.f, 0.f}, 0, 0, 0);

    // register online softmax (lane owns query w*16+m, 32 j-values)
    float mx = -1e30f;
    #pragma unroll
    for (int t = 0; t < 8; ++t)
      #pragma unroll
      for (int r = 0; r < 4; ++r) mx = fmaxf(mx, s[t][r]);
    mx = fmaxf(mx, __shfl_xor(mx, 16));
    mx = fmaxf(mx, __shfl_xor(mx, 32));
    float mn = fmaxf(m_r, mx);
    float al = __expf(m_r - mn);
    m_r = mn;
    float p[8][4], sm = 0.f;
    #pragma unroll
    for (int t = 0; t < 8; ++t)
      #pragma unroll
      for (int r = 0; r < 4; ++r) {
        p[t][r] = __expf(s[t][r] - mn);
        sm += p[t][r];
      }
    sm += __shfl_xor(sm, 16);
    sm += __shfl_xor(sm, 32);
    l_r = l_r * al + sm;

    #pragma unroll
    for (int t = 0; t < 8; ++t) {
      u32 lo = (u32)f2bf(p[t][0]) | ((u32)f2bf(p[t][1]) << 16);
      u32 hi = (u32)f2bf(p[t][2]) | ((u32)f2bf(p[t][3]) << 16);
      *(uint2*)&ps[buf][w * 16 + m][t * 16 + quad * 4] = make_uint2(lo, hi);
    }
    if (quad == 0) als[buf][w * 16 + m] = al;

    __syncthreads();

    // prefetch next tile AFTER the barrier (barrier drain won't wait on it)
    const int jn = j0 + 128;
    bf16x8 kAn[8], vBn[2][4];
    if (jn < jend) {
      #pragma unroll
      for (int t = 0; t < 8; ++t)
        kAn[t] = *(const bf16x8*)(kbase + (size_t)(jn + t * 16 + m) * C8_ + quad * 8);
      #pragma unroll
      for (int ct = 0; ct < 2; ++ct)
        #pragma unroll
        for (int kk = 0; kk < 4; ++kk)
          vBn[ct][kk] = *(const bf16x8*)(vrow + (size_t)ct * 16 * N_ + jn + kk * 32 + quad * 8);
    }

    // conditional O rescale (max updates become rare after early tiles)
    float4 alv[4];
    #pragma unroll
    for (int t = 0; t < 4; ++t) alv[t] = *(const float4*)&als[buf][t * 16 + quad * 4];
    float am = 1.f;
    #pragma unroll
    for (int t = 0; t < 4; ++t)
      am = fminf(am, fminf(fminf(alv[t].x, alv[t].y), fminf(alv[t].z, alv[t].w)));
    if (__any(am < 1.f)) {
      #pragma unroll
      for (int t = 0; t < 4; ++t)
        #pragma unroll
        for (int ct = 0; ct < 4; ++ct) {
          o[t][ct][0] *= alv[t].x; o[t][ct][1] *= alv[t].y;
          o[t][ct][2] *= alv[t].z; o[t][ct][3] *= alv[t].w;
        }
    }

    // PV: O[64q x 64c] += P[64 x 128] V^T[128 x 64]
    #pragma unroll
    for (int t = 0; t < 4; ++t) {
      #pragma unroll
      for (int kk = 0; kk < 4; ++kk) {
        bf16x8 pf = *(const bf16x8*)&ps[buf][t * 16 + m][kk * 32 + quad * 8];
        o[t][0] = __builtin_amdgcn_mfma_f32_16x16x32_bf16(pf, vB01[0][kk], o[t][0], 0, 0, 0);
        o[t][1] = __builtin_amdgcn_mfma_f32_16x16x32_bf16(pf, vB01[1][kk], o[t][1], 0, 0, 0);
        o[t][2] = __builtin_amdgcn_mfma_f32_16x16x32_bf16(pf, vB23[0][kk], o[t][2], 0, 0, 0);
        o[t][3] = __builtin_amdgcn_mfma_f32_16x16x32_bf16(pf, vB23[1][kk], o[t][3], 0, 0, 0);
      }
    }

    if (jn < jend) {
      #pragma unroll
      for (int t = 0; t < 8; ++t) kA[t] = kAn[t];
      #pragma unroll
      for (int ct = 0; ct < 2; ++ct)
        #pragma unroll
        for (int kk = 0; kk < 4; ++kk) vB01[ct][kk] = vBn[ct][kk];
    }
  }

  float* Ob = Opart + (size_t)ksl * B_ * N_ * C_ + ((size_t)b * N_ + i0) * C_ + w * 64;
  #pragma unroll
  for (int t = 0; t < 4; ++t)
    #pragma unroll
    for (int ct = 0; ct < 4; ++ct)
      #pragma unroll
      for (int r = 0; r < 4; ++r)
        Ob[(size_t)(t * 16 + quad * 4 + r) * C_ + ct * 16 + m] = o[t][ct][r];

  if (quad == 0) {
    size_t mli = ((size_t)ksl * B_ + b) * N_ + i0 + w * 16 + m;
    ml[mli] = m_r;
    ml[(size_t)2 * B_ * N_ + mli] = l_r;
  }
}

// ---------------------------------------------------------------------------
// Fused split-K combine + final 1x1 conv + residual:
//   h[n,c] = (O0*w0 + O1*w1)   (w0,w1 per-row scalars -> per-lane in B-frag)
//   out = Wo(hi/lo) * (h, xT) + bo    -> f32 (B,C,N)
// grid (N/32, B), block 256.
// ---------------------------------------------------------------------------
__global__ __launch_bounds__(256) void out_mfma(
    const float* __restrict__ Opart, const float* __restrict__ ml,
    const u16* __restrict__ xTh,
    const u16* __restrict__ WoH, const u16* __restrict__ WoL,
    const float* __restrict__ bo, float* __restrict__ out)
{
  const int tid = threadIdx.x;
  const int lane = tid & 63, w = tid >> 6, m = lane & 15, quad = lane >> 4;
  const int b = blockIdx.y, n0 = blockIdx.x * 32;
  constexpr size_t BN = (size_t)B_ * N_;

  float w0[2], w1[2];
  size_t nrow[2];
  #pragma unroll
  for (int nt = 0; nt < 2; ++nt) {
    nrow[nt] = (size_t)b * N_ + n0 + nt * 16 + m;
    float m0 = ml[nrow[nt]], m1 = ml[BN + nrow[nt]];
    float l0 = ml[2 * BN + nrow[nt]], l1 = ml[3 * BN + nrow[nt]];
    float M = fmaxf(m0, m1);
    float a0 = __expf(m0 - M), a1 = __expf(m1 - M);
    float inv = 1.f / (l0 * a0 + l1 * a1);
    w0[nt] = a0 * inv; w1[nt] = a1 * inv;
  }

  f32x4 o[4][2];
  #pragma unroll
  for (int dt = 0; dt < 4; ++dt)
    #pragma unroll
    for (int nt = 0; nt < 2; ++nt) o[dt][nt] = (f32x4){0.f, 0.f, 0.f, 0.f};

  for (int K = 0; K < 8; ++K) {
    const int ko = K * 32 + quad * 8;
    bf16x8 hf[2], xf[2];
    #pragma unroll
    for (int nt = 0; nt < 2; ++nt) {
      const float* O0 = Opart + nrow[nt] * C_ + ko;
      const float* O1 = O0 + BN * C_;
      float4 a = *(const float4*)O0,  a2 = *(const float4*)(O0 + 4);
      float4 c = *(const float4*)O1,  c2 = *(const float4*)(O1 + 4);
      float hv[8] = {
        a.x * w0[nt] + c.x * w1[nt],  a.y * w0[nt] + c.y * w1[nt],
        a.z * w0[nt] + c.z * w1[nt],  a.w * w0[nt] + c.w * w1[nt],
        a2.x * w0[nt] + c2.x * w1[nt], a2.y * w0[nt] + c2.y * w1[nt],
        a2.z * w0[nt] + c2.z * w1[nt], a2.w * w0[nt] + c2.w * w1[nt] };
      uint4 pk;
      pk.x = (u32)f2bf(hv[0]) | ((u32)f2bf(hv[1]) << 16);
      pk.y = (u32)f2bf(hv[2]) | ((u32)f2bf(hv[3]) << 16);
      pk.z = (u32)f2bf(hv[4]) | ((u32)f2bf(hv[5]) << 16);
      pk.w = (u32)f2bf(hv[6]) | ((u32)f2bf(hv[7]) << 16);
      hf[nt] = *(const bf16x8*)&pk;
      xf[nt] = *(const bf16x8*)(xTh + nrow[nt] * C_ + ko);
    }
    #pragma unroll
    for (int dt = 0; dt < 4; ++dt) {
      bf16x8 whi = *(const bf16x8*)(WoH + (size_t)(64 * w + dt * 16 + m) * C_ + ko);
      bf16x8 wlo = *(const bf16x8*)(WoL + (size_t)(64 * w + dt * 16 + m) * C_ + ko);
      #pragma unroll
      for (int nt = 0; nt < 2; ++nt) {
        o[dt][nt] = __builtin_amdgcn_mfma_f32_16x16x32_bf16(whi, hf[nt], o[dt][nt], 0, 0, 0);
        o[dt][nt] = __builtin_amdgcn_mfma_f32_16x16x32_bf16(wlo, hf[nt], o[dt][nt], 0, 0, 0);
        o[dt][nt] = __builtin_amdgcn_mfma_f32_16x16x32_bf16(whi, xf[nt], o[dt][nt], 0, 0, 0);
        o[dt][nt] = __builtin_amdgcn_mfma_f32_16x16x32_bf16(wlo, xf[nt], o[dt][nt], 0, 0, 0);
      }
    }
  }

  #pragma unroll
  for (int dt = 0; dt < 4; ++dt)
    #pragma unroll
    for (int r = 0; r < 4; ++r) {
      int d = 64 * w + dt * 16 + quad * 4 + r;
      float bias = bo[d];
      #pragma unroll
      for (int nt = 0; nt < 2; ++nt)
        out[((size_t)b * C_ + d) * N_ + n0 + nt * 16 + m] = o[dt][nt][r] + bias;
    }
}

// ---------------------------------------------------------------------------
extern "C" void kernel_launch(void* const* d_in, const int* in_sizes, int n_in,
                              void* d_out, int out_size, void* d_ws, size_t ws_size,
                              hipStream_t stream)
{
  const float* x  = (const float*)d_in[0];
  const float* Wq = (const float*)d_in[1];
  const float* bq = (const float*)d_in[2];
  const float* Wk = (const float*)d_in[3];
  const float* bk = (const float*)d_in[4];
  const float* Wv = (const float*)d_in[5];
  const float* bv = (const float*)d_in[6];
  const float* Wo = (const float*)d_in[7];
  const float* bo = (const float*)d_in[8];

  // workspace layout (~58.8 MB)
  u16* p = (u16*)d_ws;
  u16* qt  = p;  p += (size_t)B_ * N_ * C8_;   // 1 MB
  u16* kt  = p;  p += (size_t)B_ * N_ * C8_;   // 1 MB
  u16* vb  = p;  p += (size_t)B_ * C_ * N_;    // 8 MB
  u16* xTh = p;  p += (size_t)B_ * N_ * C_;    // 8 MB
  u16* xTl = p;  p += (size_t)B_ * N_ * C_;    // 8 MB
  u16* WqH = p;  p += 8192;
  u16* WqL = p;  p += 8192;
  u16* WkH = p;  p += 8192;
  u16* WkL = p;  p += 8192;
  u16* WvH = p;  p += 65536;
  u16* WvL = p;  p += 65536;
  u16* WoH = p;  p += 65536;
  u16* WoL = p;  p += 65536;
  float* Opart = (float*)p;                    // 32 MB
  float* ml = Opart + (size_t)2 * B_ * N_ * C_; // 256 KB

  float* out = (float*)d_out;

  wsplit<<<576, 256, 0, stream>>>(Wq, Wk, Wv, Wo,
      WqH, WqL, WkH, WkL, WvH, WvL, WoH, WoL);
  xprep<<<dim3(N_ / 64, C_ / 64, B_), 256, 0, stream>>>(x, xTh, xTl);
  qkv_mfma<<<dim3(N_ / 32, B_), 256, 0, stream>>>(
      xTh, xTl, WqH, WqL, WkH, WkL, WvH, WvL, bq, bk, bv, qt, kt, vb);
  attn_mfma<<<dim3(N_ / 64, 2, B_), 256, 0, stream>>>(qt, kt, vb, Opart, ml);
  out_mfma<<<dim3(N_ / 32, B_), 256, 0, stream>>>(Opart, ml, xTh, WoH, WoL, bo, out);
}

// Round 7
// 216.658 us; speedup vs baseline: 1.1966x; 1.1966x over previous
//
#include <hip/hip_runtime.h>

#define DEV __device__ __forceinline__

constexpr int B_  = 4;
constexpr int C_  = 256;
constexpr int C8_ = 32;
constexpr int N_  = 4096;   // 64*64
constexpr float LOG2E = 1.4426950408889634f;

using u16 = unsigned short;
using u32 = unsigned int;

typedef __attribute__((ext_vector_type(8))) short bf16x8;
typedef __attribute__((ext_vector_type(4))) float f32x4;

DEV float bf2f(u16 u) { return __uint_as_float(((u32)u) << 16); }
DEV u16   f2bf(float f) {
  u32 i = __float_as_uint(f);
  i += 0x7fffu + ((i >> 16) & 1u);   // round-to-nearest-even
  return (u16)(i >> 16);
}

// LDS-only barrier: the sole cross-wave data is in LDS, so wait lgkm only —
// avoids the compiler's vmcnt(0) drain that stalls on outstanding K/V loads.
DEV void lds_barrier() {
  asm volatile("s_waitcnt lgkmcnt(0)\n\ts_barrier" ::: "memory");
}

// ---------------------------------------------------------------------------
// Weight prep: Wq*log2e, Wk -> hi/lo; Wv -> hi only; Wo -> hi/lo.
// 147456 = 576*256 threads.
// ---------------------------------------------------------------------------
__global__ __launch_bounds__(256) void wsplit(
    const float* __restrict__ Wq, const float* __restrict__ Wk,
    const float* __restrict__ Wv, const float* __restrict__ Wo,
    u16* __restrict__ WqH, u16* __restrict__ WqL,
    u16* __restrict__ WkH, u16* __restrict__ WkL,
    u16* __restrict__ WvH,
    u16* __restrict__ WoH, u16* __restrict__ WoL)
{
  int i = blockIdx.x * 256 + threadIdx.x;
  if (i < 8192) {
    float v = Wq[i] * LOG2E;
    u16 h = f2bf(v); WqH[i] = h; WqL[i] = f2bf(v - bf2f(h));
  } else if (i < 16384) {
    int off = i - 8192;
    float v = Wk[off];
    u16 h = f2bf(v); WkH[off] = h; WkL[off] = f2bf(v - bf2f(h));
  } else if (i < 81920) {
    int off = i - 16384;
    WvH[off] = f2bf(Wv[off]);
  } else {
    int off = i - 81920;
    float v = Wo[off];
    u16 h = f2bf(v); WoH[off] = h; WoL[off] = f2bf(v - bf2f(h));
  }
}

// ---------------------------------------------------------------------------
// x (B,C,N) f32 -> xTh, xTl (B,N,C) bf16 hi/lo (transpose via LDS).
// grid (N/64, C/64, B), block 256.
// ---------------------------------------------------------------------------
__global__ __launch_bounds__(256) void xprep(
    const float* __restrict__ x, u16* __restrict__ xTh, u16* __restrict__ xTl)
{
  __shared__ float tf[64][65];
  const int tid = threadIdx.x;
  const int b = blockIdx.z, c0 = blockIdx.y * 64, n0 = blockIdx.x * 64;
  const int nl = tid & 63, cb = tid >> 6;

  #pragma unroll
  for (int cc = 0; cc < 16; ++cc) {
    int cl = cb * 16 + cc;
    tf[nl][cl] = x[((size_t)b * C_ + c0 + cl) * N_ + n0 + nl];
  }
  __syncthreads();

  #pragma unroll
  for (int it = 0; it < 2; ++it) {
    int idx = tid + it * 256;
    int n = idx >> 3, q = idx & 7;
    u32 ph[4], pl[4];
    #pragma unroll
    for (int j = 0; j < 4; ++j) {
      float v0 = tf[n][q * 8 + 2 * j], v1 = tf[n][q * 8 + 2 * j + 1];
      u16 h0 = f2bf(v0), h1 = f2bf(v1);
      ph[j] = (u32)h0 | ((u32)h1 << 16);
      pl[j] = (u32)f2bf(v0 - bf2f(h0)) | ((u32)f2bf(v1 - bf2f(h1)) << 16);
    }
    size_t off = ((size_t)b * N_ + n0 + n) * C_ + c0 + q * 8;
    *(uint4*)&xTh[off] = make_uint4(ph[0], ph[1], ph[2], ph[3]);
    *(uint4*)&xTl[off] = make_uint4(pl[0], pl[1], pl[2], pl[3]);
  }
}

// ---------------------------------------------------------------------------
// q/k/v projections, LDS-staged x fragments.
// grid (N/32, B), block 256.  wave 0-1: q, 2-3: k; all waves: v 64-ch slice.
//   q/k: 3-term hi/lo (accurate scores); v: hi-only (error uncritical).
// ---------------------------------------------------------------------------
__global__ __launch_bounds__(256) void qkv_mfma(
    const u16* __restrict__ xTh, const u16* __restrict__ xTl,
    const u16* __restrict__ WqH, const u16* __restrict__ WqL,
    const u16* __restrict__ WkH, const u16* __restrict__ WkL,
    const u16* __restrict__ WvH,
    const float* __restrict__ bq, const float* __restrict__ bk,
    const float* __restrict__ bv,
    u16* __restrict__ qt, u16* __restrict__ kt, u16* __restrict__ vb)
{
  __shared__ __align__(16) u16 xsh[32][270];   // stride 270 elems = 135 dw (7 mod 32)
  __shared__ __align__(16) u16 xsl[32][270];

  const int tid = threadIdx.x;
  const int lane = tid & 63, w = tid >> 6, m = lane & 15, quad = lane >> 4;
  const int b = blockIdx.y, n0 = blockIdx.x * 32;

  #pragma unroll
  for (int it = 0; it < 4; ++it) {
    int chunk = tid + it * 256;
    int row = chunk >> 5, col = (chunk & 31) * 8;
    size_t g = ((size_t)b * N_ + n0 + row) * C_ + col;
    *(uint4*)&xsh[row][col] = *(const uint4*)(xTh + g);
    *(uint4*)&xsl[row][col] = *(const uint4*)(xTl + g);
  }
  __syncthreads();

  const u16* qkH = (w < 2) ? (WqH + (size_t)(w * 16 + m) * C_)
                           : (WkH + (size_t)((w - 2) * 16 + m) * C_);
  const u16* qkL = (w < 2) ? (WqL + (size_t)(w * 16 + m) * C_)
                           : (WkL + (size_t)((w - 2) * 16 + m) * C_);

  f32x4 ov[4][2], oq[2];
  #pragma unroll
  for (int dt = 0; dt < 4; ++dt)
    #pragma unroll
    for (int nt = 0; nt < 2; ++nt) ov[dt][nt] = (f32x4){0.f, 0.f, 0.f, 0.f};
  #pragma unroll
  for (int nt = 0; nt < 2; ++nt) oq[nt] = (f32x4){0.f, 0.f, 0.f, 0.f};

  for (int K = 0; K < 8; ++K) {
    const int ko = K * 32 + quad * 8;
    bf16x8 xh[2], xl[2];
    #pragma unroll
    for (int nt = 0; nt < 2; ++nt) {
      xh[nt] = *(const bf16x8*)&xsh[nt * 16 + m][ko];
      xl[nt] = *(const bf16x8*)&xsl[nt * 16 + m][ko];
    }
    #pragma unroll
    for (int dt = 0; dt < 4; ++dt) {
      bf16x8 whi = *(const bf16x8*)(WvH + (size_t)(64 * w + dt * 16 + m) * C_ + ko);
      #pragma unroll
      for (int nt = 0; nt < 2; ++nt)
        ov[dt][nt] = __builtin_amdgcn_mfma_f32_16x16x32_bf16(whi, xh[nt], ov[dt][nt], 0, 0, 0);
    }
    {
      bf16x8 bhi = *(const bf16x8*)(qkH + ko);
      bf16x8 blo = *(const bf16x8*)(qkL + ko);
      #pragma unroll
      for (int nt = 0; nt < 2; ++nt) {
        oq[nt] = __builtin_amdgcn_mfma_f32_16x16x32_bf16(xh[nt], bhi, oq[nt], 0, 0, 0);
        oq[nt] = __builtin_amdgcn_mfma_f32_16x16x32_bf16(xl[nt], bhi, oq[nt], 0, 0, 0);
        oq[nt] = __builtin_amdgcn_mfma_f32_16x16x32_bf16(xh[nt], blo, oq[nt], 0, 0, 0);
      }
    }
  }

  #pragma unroll
  for (int dt = 0; dt < 4; ++dt)
    #pragma unroll
    for (int r = 0; r < 4; ++r) {
      int oc = 64 * w + dt * 16 + quad * 4 + r;
      float bias = bv[oc];
      #pragma unroll
      for (int nt = 0; nt < 2; ++nt)
        vb[((size_t)b * C_ + oc) * N_ + n0 + nt * 16 + m] = f2bf(ov[dt][nt][r] + bias);
    }
  {
    u16* qk_out = (w < 2) ? qt : kt;
    int dbase = (w & 1) * 16;
    float bias = (w < 2) ? bq[dbase + m] * LOG2E : bk[dbase + m];
    #pragma unroll
    for (int nt = 0; nt < 2; ++nt)
      #pragma unroll
      for (int r = 0; r < 4; ++r)
        qk_out[((size_t)b * N_ + n0 + nt * 16 + quad * 4 + r) * C8_ + dbase + m] =
            f2bf(oq[nt][r] + bias);
  }
}

// ---------------------------------------------------------------------------
// MFMA flash attention, split-K=2, TJ=128.  r5 structure (no explicit
// pipeline) + lgkm-only barrier + exp2-domain softmax (q pre-scaled).
// grid (N/64, 2, B) linearized+swizzled; block 256 (4 waves).
// ---------------------------------------------------------------------------
__global__ __launch_bounds__(256) void attn_mfma(
    const u16* __restrict__ qt, const u16* __restrict__ kt,
    const u16* __restrict__ vb,
    float* __restrict__ Opart, float* __restrict__ ml)
{
  __shared__ __align__(16) u16  ps[2][64][136];
  __shared__ __align__(16) float als[2][64];

  const int tid = threadIdx.x, lane = tid & 63, w = tid >> 6;
  const int m = lane & 15, quad = lane >> 4;

  const int lid = blockIdx.x + gridDim.x * (blockIdx.y + gridDim.y * blockIdx.z);
  const int grp = lid & 7, ksl = grp & 1, b = grp >> 1;
  const int i0 = (lid >> 3) * 64;

  const bf16x8 qfrag =
      *(const bf16x8*)(qt + ((size_t)b * N_ + i0 + w * 16 + m) * C8_ + quad * 8);
  const u16* kbase = kt + (size_t)b * N_ * C8_;
  const u16* vrow  = vb + ((size_t)b * C_ + w * 64 + m) * N_;

  f32x4 o[4][4];
  #pragma unroll
  for (int t = 0; t < 4; ++t)
    #pragma unroll
    for (int ct = 0; ct < 4; ++ct) o[t][ct] = (f32x4){0.f, 0.f, 0.f, 0.f};
  float m_r = -1e30f, l_r = 0.f;

  const int jbeg = ksl * 2048, jend = jbeg + 2048;
  int buf = 0;

  for (int j0 = jbeg; j0 < jend; j0 += 128, buf ^= 1) {
    bf16x8 kA[8];
    #pragma unroll
    for (int t = 0; t < 8; ++t)
      kA[t] = *(const bf16x8*)(kbase + (size_t)(j0 + t * 16 + m) * C8_ + quad * 8);
    bf16x8 vB[4][4];
    #pragma unroll
    for (int ct = 0; ct < 4; ++ct)
      #pragma unroll
      for (int kk = 0; kk < 4; ++kk)
        vB[ct][kk] = *(const bf16x8*)(vrow + (size_t)ct * 16 * N_ + j0 + kk * 32 + quad * 8);

    // S^T[j][q] in log2 domain (q pre-scaled by log2e)
    f32x4 s[8];
    #pragma unroll
    for (int t = 0; t < 8; ++t)
      s[t] = __builtin_amdgcn_mfma_f32_16x16x32_bf16(
          kA[t], qfrag, (f32x4){0.f, 0.f, 0.f, 0.f}, 0, 0, 0);

    float mx = -1e30f;
    #pragma unroll
    for (int t = 0; t < 8; ++t)
      #pragma unroll
      for (int r = 0; r < 4; ++r) mx = fmaxf(mx, s[t][r]);
    mx = fmaxf(mx, __shfl_xor(mx, 16));
    mx = fmaxf(mx, __shfl_xor(mx, 32));
    float mn = fmaxf(m_r, mx);
    float al = exp2f(m_r - mn);
    m_r = mn;
    float p[8][4], sm = 0.f;
    #pragma unroll
    for (int t = 0; t < 8; ++t)
      #pragma unroll
      for (int r = 0; r < 4; ++r) {
        p[t][r] = exp2f(s[t][r] - mn);
        sm += p[t][r];
      }
    sm += __shfl_xor(sm, 16);
    sm += __shfl_xor(sm, 32);
    l_r = l_r * al + sm;

    #pragma unroll
    for (int t = 0; t < 8; ++t) {
      u32 lo = (u32)f2bf(p[t][0]) | ((u32)f2bf(p[t][1]) << 16);
      u32 hi = (u32)f2bf(p[t][2]) | ((u32)f2bf(p[t][3]) << 16);
      *(uint2*)&ps[buf][w * 16 + m][t * 16 + quad * 4] = make_uint2(lo, hi);
    }
    if (quad == 0) als[buf][w * 16 + m] = al;

    lds_barrier();   // LDS-visibility only; K/V loads stay outstanding

    #pragma unroll
    for (int t = 0; t < 4; ++t) {
      float4 alv = *(const float4*)&als[buf][t * 16 + quad * 4];
      #pragma unroll
      for (int ct = 0; ct < 4; ++ct) {
        o[t][ct][0] *= alv.x; o[t][ct][1] *= alv.y;
        o[t][ct][2] *= alv.z; o[t][ct][3] *= alv.w;
      }
    }

    #pragma unroll
    for (int t = 0; t < 4; ++t) {
      #pragma unroll
      for (int kk = 0; kk < 4; ++kk) {
        bf16x8 pf = *(const bf16x8*)&ps[buf][t * 16 + m][kk * 32 + quad * 8];
        #pragma unroll
        for (int ct = 0; ct < 4; ++ct)
          o[t][ct] = __builtin_amdgcn_mfma_f32_16x16x32_bf16(pf, vB[ct][kk], o[t][ct], 0, 0, 0);
      }
    }
  }

  float* Ob = Opart + (size_t)ksl * B_ * N_ * C_ + ((size_t)b * N_ + i0) * C_ + w * 64;
  #pragma unroll
  for (int t = 0; t < 4; ++t)
    #pragma unroll
    for (int ct = 0; ct < 4; ++ct)
      #pragma unroll
      for (int r = 0; r < 4; ++r)
        Ob[(size_t)(t * 16 + quad * 4 + r) * C_ + ct * 16 + m] = o[t][ct][r];

  if (quad == 0) {
    size_t mli = ((size_t)ksl * B_ + b) * N_ + i0 + w * 16 + m;
    ml[mli] = m_r;
    ml[(size_t)2 * B_ * N_ + mli] = l_r;
  }
}

// ---------------------------------------------------------------------------
// Fused split-K combine + residual:  h'[b,n,c] = O0*w0 + O1*w1 + x  (bf16)
// Fully coalesced row-major IO.  grid (N/64, B), block 256.
// ---------------------------------------------------------------------------
__global__ __launch_bounds__(256) void combine_h(
    const float* __restrict__ Opart, const float* __restrict__ ml,
    const u16* __restrict__ xTh, u16* __restrict__ hB)
{
  const int tid = threadIdx.x;
  const int b = blockIdx.y, n0 = blockIdx.x * 64;
  constexpr size_t BN = (size_t)B_ * N_;
  const int lanec = tid & 15;

  #pragma unroll
  for (int pass = 0; pass < 4; ++pass) {
    int row = (tid >> 4) + pass * 16;
    size_t nrow = (size_t)b * N_ + n0 + row;
    float m0 = ml[nrow], m1 = ml[BN + nrow];
    float l0 = ml[2 * BN + nrow], l1 = ml[3 * BN + nrow];
    float M = fmaxf(m0, m1);
    float a0 = exp2f(m0 - M), a1 = exp2f(m1 - M);
    float inv = 1.f / (l0 * a0 + l1 * a1);
    float w0 = a0 * inv, w1 = a1 * inv;

    const float* O0 = Opart + nrow * C_;
    const float* O1 = O0 + BN * C_;
    #pragma unroll
    for (int i = 0; i < 4; ++i) {
      int c = lanec * 4 + i * 64;
      float4 a  = *(const float4*)(O0 + c);
      float4 c2 = *(const float4*)(O1 + c);
      uint2 xv = *(const uint2*)(xTh + nrow * C_ + c);
      float h0 = a.x * w0 + c2.x * w1 + bf2f((u16)(xv.x & 0xffff));
      float h1 = a.y * w0 + c2.y * w1 + bf2f((u16)(xv.x >> 16));
      float h2 = a.z * w0 + c2.z * w1 + bf2f((u16)(xv.y & 0xffff));
      float h3 = a.w * w0 + c2.w * w1 + bf2f((u16)(xv.y >> 16));
      u32 lo = (u32)f2bf(h0) | ((u32)f2bf(h1) << 16);
      u32 hi = (u32)f2bf(h2) | ((u32)f2bf(h3) << 16);
      *(uint2*)&hB[nrow * C_ + c] = make_uint2(lo, hi);
    }
  }
}

// ---------------------------------------------------------------------------
// Final 1x1 conv: out = Wo(hi/lo) * h' + bo  -> f32 (B,C,N)
// h' LDS-staged.  grid (N/32, B), block 256; wave w = d-range [64w,64w+64).
// ---------------------------------------------------------------------------
__global__ __launch_bounds__(256) void out_mfma(
    const u16* __restrict__ hB,
    const u16* __restrict__ WoH, const u16* __restrict__ WoL,
    const float* __restrict__ bo, float* __restrict__ out)
{
  __shared__ __align__(16) u16 hs[32][270];

  const int tid = threadIdx.x;
  const int lane = tid & 63, w = tid >> 6, m = lane & 15, quad = lane >> 4;
  const int b = blockIdx.y, n0 = blockIdx.x * 32;

  #pragma unroll
  for (int it = 0; it < 4; ++it) {
    int chunk = tid + it * 256;
    int row = chunk >> 5, col = (chunk & 31) * 8;
    *(uint4*)&hs[row][col] = *(const uint4*)(hB + ((size_t)b * N_ + n0 + row) * C_ + col);
  }
  __syncthreads();

  f32x4 o[4][2];
  #pragma unroll
  for (int dt = 0; dt < 4; ++dt)
    #pragma unroll
    for (int nt = 0; nt < 2; ++nt) o[dt][nt] = (f32x4){0.f, 0.f, 0.f, 0.f};

  for (int K = 0; K < 8; ++K) {
    const int ko = K * 32 + quad * 8;
    bf16x8 hf[2];
    #pragma unroll
    for (int nt = 0; nt < 2; ++nt) hf[nt] = *(const bf16x8*)&hs[nt * 16 + m][ko];
    #pragma unroll
    for (int dt = 0; dt < 4; ++dt) {
      bf16x8 whi = *(const bf16x8*)(WoH + (size_t)(64 * w + dt * 16 + m) * C_ + ko);
      bf16x8 wlo = *(const bf16x8*)(WoL + (size_t)(64 * w + dt * 16 + m) * C_ + ko);
      #pragma unroll
      for (int nt = 0; nt < 2; ++nt) {
        o[dt][nt] = __builtin_amdgcn_mfma_f32_16x16x32_bf16(whi, hf[nt], o[dt][nt], 0, 0, 0);
        o[dt][nt] = __builtin_amdgcn_mfma_f32_16x16x32_bf16(wlo, hf[nt], o[dt][nt], 0, 0, 0);
      }
    }
  }

  #pragma unroll
  for (int dt = 0; dt < 4; ++dt)
    #pragma unroll
    for (int r = 0; r < 4; ++r) {
      int d = 64 * w + dt * 16 + quad * 4 + r;
      float bias = bo[d];
      #pragma unroll
      for (int nt = 0; nt < 2; ++nt)
        out[((size_t)b * C_ + d) * N_ + n0 + nt * 16 + m] = o[dt][nt][r] + bias;
    }
}

// ---------------------------------------------------------------------------
extern "C" void kernel_launch(void* const* d_in, const int* in_sizes, int n_in,
                              void* d_out, int out_size, void* d_ws, size_t ws_size,
                              hipStream_t stream)
{
  const float* x  = (const float*)d_in[0];
  const float* Wq = (const float*)d_in[1];
  const float* bq = (const float*)d_in[2];
  const float* Wk = (const float*)d_in[3];
  const float* bk = (const float*)d_in[4];
  const float* Wv = (const float*)d_in[5];
  const float* bv = (const float*)d_in[6];
  const float* Wo = (const float*)d_in[7];
  const float* bo = (const float*)d_in[8];

  // workspace layout (~67 MB)
  u16* p = (u16*)d_ws;
  u16* qt  = p;  p += (size_t)B_ * N_ * C8_;   // 1 MB
  u16* kt  = p;  p += (size_t)B_ * N_ * C8_;   // 1 MB
  u16* vb  = p;  p += (size_t)B_ * C_ * N_;    // 8 MB
  u16* xTh = p;  p += (size_t)B_ * N_ * C_;    // 8 MB
  u16* xTl = p;  p += (size_t)B_ * N_ * C_;    // 8 MB
  u16* hB  = p;  p += (size_t)B_ * N_ * C_;    // 8 MB
  u16* WqH = p;  p += 8192;
  u16* WqL = p;  p += 8192;
  u16* WkH = p;  p += 8192;
  u16* WkL = p;  p += 8192;
  u16* WvH = p;  p += 65536;
  u16* WoH = p;  p += 65536;
  u16* WoL = p;  p += 65536;
  float* Opart = (float*)p;                     // 32 MB
  float* ml = Opart + (size_t)2 * B_ * N_ * C_; // 256 KB

  float* out = (float*)d_out;

  wsplit<<<576, 256, 0, stream>>>(Wq, Wk, Wv, Wo,
      WqH, WqL, WkH, WkL, WvH, WoH, WoL);
  xprep<<<dim3(N_ / 64, C_ / 64, B_), 256, 0, stream>>>(x, xTh, xTl);
  qkv_mfma<<<dim3(N_ / 32, B_), 256, 0, stream>>>(
      xTh, xTl, WqH, WqL, WkH, WkL, WvH, bq, bk, bv, qt, kt, vb);
  attn_mfma<<<dim3(N_ / 64, 2, B_), 256, 0, stream>>>(qt, kt, vb, Opart, ml);
  combine_h<<<dim3(N_ / 64, B_), 256, 0, stream>>>(Opart, ml, xTh, hB);
  out_mfma<<<dim3(N_ / 32, B_), 256, 0, stream>>>(hB, WoH, WoL, bo, out);
}

// Round 8
// 212.458 us; speedup vs baseline: 1.2202x; 1.0198x over previous
//
#include <hip/hip_runtime.h>

#define DEV __device__ __forceinline__

constexpr int B_  = 4;
constexpr int C_  = 256;
constexpr int C8_ = 32;
constexpr int N_  = 4096;   // 64*64
constexpr float LOG2E = 1.4426950408889634f;

using u16 = unsigned short;
using u32 = unsigned int;

typedef __attribute__((ext_vector_type(8))) short bf16x8;
typedef __attribute__((ext_vector_type(4))) float f32x4;

DEV float bf2f(u16 u) { return __uint_as_float(((u32)u) << 16); }
DEV u16   f2bf(float f) {
  u32 i = __float_as_uint(f);
  i += 0x7fffu + ((i >> 16) & 1u);   // round-to-nearest-even
  return (u16)(i >> 16);
}
// pack two floats to bf16x2 (RTZ) in ONE v_perm_b32
DEV u32 pack_rtz(float a, float b) {
  return __builtin_amdgcn_perm(__float_as_uint(b), __float_as_uint(a), 0x07060302);
}

// LDS-only barrier: cross-wave data is in LDS only -> skip the vmcnt(0) drain
DEV void lds_barrier() {
  asm volatile("s_waitcnt lgkmcnt(0)\n\ts_barrier" ::: "memory");
}

// ---------------------------------------------------------------------------
// Weight prep: Wq*log2e, Wk -> hi/lo; Wv -> hi only; Wo -> hi/lo.
// ---------------------------------------------------------------------------
__global__ __launch_bounds__(256) void wsplit(
    const float* __restrict__ Wq, const float* __restrict__ Wk,
    const float* __restrict__ Wv, const float* __restrict__ Wo,
    u16* __restrict__ WqH, u16* __restrict__ WqL,
    u16* __restrict__ WkH, u16* __restrict__ WkL,
    u16* __restrict__ WvH,
    u16* __restrict__ WoH, u16* __restrict__ WoL)
{
  int i = blockIdx.x * 256 + threadIdx.x;
  if (i < 8192) {
    float v = Wq[i] * LOG2E;
    u16 h = f2bf(v); WqH[i] = h; WqL[i] = f2bf(v - bf2f(h));
  } else if (i < 16384) {
    int off = i - 8192;
    float v = Wk[off];
    u16 h = f2bf(v); WkH[off] = h; WkL[off] = f2bf(v - bf2f(h));
  } else if (i < 81920) {
    int off = i - 16384;
    WvH[off] = f2bf(Wv[off]);
  } else {
    int off = i - 81920;
    float v = Wo[off];
    u16 h = f2bf(v); WoH[off] = h; WoL[off] = f2bf(v - bf2f(h));
  }
}

// ---------------------------------------------------------------------------
// x (B,C,N) f32 -> xTh, xTl (B,N,C) bf16 hi/lo (transpose via LDS).
// grid (N/64, C/64, B), block 256.
// ---------------------------------------------------------------------------
__global__ __launch_bounds__(256) void xprep(
    const float* __restrict__ x, u16* __restrict__ xTh, u16* __restrict__ xTl)
{
  __shared__ float tf[64][65];
  const int tid = threadIdx.x;
  const int b = blockIdx.z, c0 = blockIdx.y * 64, n0 = blockIdx.x * 64;
  const int nl = tid & 63, cb = tid >> 6;

  #pragma unroll
  for (int cc = 0; cc < 16; ++cc) {
    int cl = cb * 16 + cc;
    tf[nl][cl] = x[((size_t)b * C_ + c0 + cl) * N_ + n0 + nl];
  }
  __syncthreads();

  #pragma unroll
  for (int it = 0; it < 2; ++it) {
    int idx = tid + it * 256;
    int n = idx >> 3, q = idx & 7;
    u32 ph[4], pl[4];
    #pragma unroll
    for (int j = 0; j < 4; ++j) {
      float v0 = tf[n][q * 8 + 2 * j], v1 = tf[n][q * 8 + 2 * j + 1];
      u16 h0 = f2bf(v0), h1 = f2bf(v1);
      ph[j] = (u32)h0 | ((u32)h1 << 16);
      pl[j] = (u32)f2bf(v0 - bf2f(h0)) | ((u32)f2bf(v1 - bf2f(h1)) << 16);
    }
    size_t off = ((size_t)b * N_ + n0 + n) * C_ + c0 + q * 8;
    *(uint4*)&xTh[off] = make_uint4(ph[0], ph[1], ph[2], ph[3]);
    *(uint4*)&xTl[off] = make_uint4(pl[0], pl[1], pl[2], pl[3]);
  }
}

// ---------------------------------------------------------------------------
// q/k/v projections, LDS-staged x fragments.
// grid (N/32, B), block 256.
// ---------------------------------------------------------------------------
__global__ __launch_bounds__(256) void qkv_mfma(
    const u16* __restrict__ xTh, const u16* __restrict__ xTl,
    const u16* __restrict__ WqH, const u16* __restrict__ WqL,
    const u16* __restrict__ WkH, const u16* __restrict__ WkL,
    const u16* __restrict__ WvH,
    const float* __restrict__ bq, const float* __restrict__ bk,
    const float* __restrict__ bv,
    u16* __restrict__ qt, u16* __restrict__ kt, u16* __restrict__ vb)
{
  __shared__ __align__(16) u16 xsh[32][270];
  __shared__ __align__(16) u16 xsl[32][270];

  const int tid = threadIdx.x;
  const int lane = tid & 63, w = tid >> 6, m = lane & 15, quad = lane >> 4;
  const int b = blockIdx.y, n0 = blockIdx.x * 32;

  #pragma unroll
  for (int it = 0; it < 4; ++it) {
    int chunk = tid + it * 256;
    int row = chunk >> 5, col = (chunk & 31) * 8;
    size_t g = ((size_t)b * N_ + n0 + row) * C_ + col;
    *(uint4*)&xsh[row][col] = *(const uint4*)(xTh + g);
    *(uint4*)&xsl[row][col] = *(const uint4*)(xTl + g);
  }
  __syncthreads();

  const u16* qkH = (w < 2) ? (WqH + (size_t)(w * 16 + m) * C_)
                           : (WkH + (size_t)((w - 2) * 16 + m) * C_);
  const u16* qkL = (w < 2) ? (WqL + (size_t)(w * 16 + m) * C_)
                           : (WkL + (size_t)((w - 2) * 16 + m) * C_);

  f32x4 ov[4][2], oq[2];
  #pragma unroll
  for (int dt = 0; dt < 4; ++dt)
    #pragma unroll
    for (int nt = 0; nt < 2; ++nt) ov[dt][nt] = (f32x4){0.f, 0.f, 0.f, 0.f};
  #pragma unroll
  for (int nt = 0; nt < 2; ++nt) oq[nt] = (f32x4){0.f, 0.f, 0.f, 0.f};

  for (int K = 0; K < 8; ++K) {
    const int ko = K * 32 + quad * 8;
    bf16x8 xh[2], xl[2];
    #pragma unroll
    for (int nt = 0; nt < 2; ++nt) {
      xh[nt] = *(const bf16x8*)&xsh[nt * 16 + m][ko];
      xl[nt] = *(const bf16x8*)&xsl[nt * 16 + m][ko];
    }
    #pragma unroll
    for (int dt = 0; dt < 4; ++dt) {
      bf16x8 whi = *(const bf16x8*)(WvH + (size_t)(64 * w + dt * 16 + m) * C_ + ko);
      #pragma unroll
      for (int nt = 0; nt < 2; ++nt)
        ov[dt][nt] = __builtin_amdgcn_mfma_f32_16x16x32_bf16(whi, xh[nt], ov[dt][nt], 0, 0, 0);
    }
    {
      bf16x8 bhi = *(const bf16x8*)(qkH + ko);
      bf16x8 blo = *(const bf16x8*)(qkL + ko);
      #pragma unroll
      for (int nt = 0; nt < 2; ++nt) {
        oq[nt] = __builtin_amdgcn_mfma_f32_16x16x32_bf16(xh[nt], bhi, oq[nt], 0, 0, 0);
        oq[nt] = __builtin_amdgcn_mfma_f32_16x16x32_bf16(xl[nt], bhi, oq[nt], 0, 0, 0);
        oq[nt] = __builtin_amdgcn_mfma_f32_16x16x32_bf16(xh[nt], blo, oq[nt], 0, 0, 0);
      }
    }
  }

  #pragma unroll
  for (int dt = 0; dt < 4; ++dt)
    #pragma unroll
    for (int r = 0; r < 4; ++r) {
      int oc = 64 * w + dt * 16 + quad * 4 + r;
      float bias = bv[oc];
      #pragma unroll
      for (int nt = 0; nt < 2; ++nt)
        vb[((size_t)b * C_ + oc) * N_ + n0 + nt * 16 + m] = f2bf(ov[dt][nt][r] + bias);
    }
  {
    u16* qk_out = (w < 2) ? qt : kt;
    int dbase = (w & 1) * 16;
    float bias = (w < 2) ? bq[dbase + m] * LOG2E : bk[dbase + m];
    #pragma unroll
    for (int nt = 0; nt < 2; ++nt)
      #pragma unroll
      for (int r = 0; r < 4; ++r)
        qk_out[((size_t)b * N_ + n0 + nt * 16 + quad * 4 + r) * C8_ + dbase + m] =
            f2bf(oq[nt][r] + bias);
  }
}

// ---------------------------------------------------------------------------
// MFMA flash attention, split-K=4 (4 blocks/CU), TJ=128, exp2 softmax.
// Stores NORMALIZED O (O/l) as bf16 (S,B,N,C) + per-query (m,l).
// grid (N/64, 4, B) linearized+swizzled; block 256 (4 waves).
// ---------------------------------------------------------------------------
__global__ __launch_bounds__(256) void attn_mfma(
    const u16* __restrict__ qt, const u16* __restrict__ kt,
    const u16* __restrict__ vb,
    u16* __restrict__ Onorm, float* __restrict__ ml)
{
  __shared__ __align__(16) u16  ps[2][64][136];
  __shared__ __align__(16) float als[2][64];
  __shared__ float lfin[64];

  const int tid = threadIdx.x, lane = tid & 63, w = tid >> 6;
  const int m = lane & 15, quad = lane >> 4;

  const int lid = blockIdx.x + gridDim.x * (blockIdx.y + gridDim.y * blockIdx.z);
  const int grp = lid & 15, ksl = grp & 3, b = grp >> 2;
  const int i0 = (lid >> 4) * 64;

  const bf16x8 qfrag =
      *(const bf16x8*)(qt + ((size_t)b * N_ + i0 + w * 16 + m) * C8_ + quad * 8);
  const u16* kbase = kt + (size_t)b * N_ * C8_;
  const u16* vrow  = vb + ((size_t)b * C_ + w * 64 + m) * N_;

  f32x4 o[4][4];
  #pragma unroll
  for (int t = 0; t < 4; ++t)
    #pragma unroll
    for (int ct = 0; ct < 4; ++ct) o[t][ct] = (f32x4){0.f, 0.f, 0.f, 0.f};
  float m_r = -1e30f, l_r = 0.f;

  const int jbeg = ksl * 1024, jend = jbeg + 1024;
  int buf = 0;

  for (int j0 = jbeg; j0 < jend; j0 += 128, buf ^= 1) {
    bf16x8 kA[8];
    #pragma unroll
    for (int t = 0; t < 8; ++t)
      kA[t] = *(const bf16x8*)(kbase + (size_t)(j0 + t * 16 + m) * C8_ + quad * 8);
    bf16x8 vB[4][4];
    #pragma unroll
    for (int ct = 0; ct < 4; ++ct)
      #pragma unroll
      for (int kk = 0; kk < 4; ++kk)
        vB[ct][kk] = *(const bf16x8*)(vrow + (size_t)ct * 16 * N_ + j0 + kk * 32 + quad * 8);

    // S^T[j][q] in log2 domain (q pre-scaled by log2e)
    f32x4 s[8];
    #pragma unroll
    for (int t = 0; t < 8; ++t)
      s[t] = __builtin_amdgcn_mfma_f32_16x16x32_bf16(
          kA[t], qfrag, (f32x4){0.f, 0.f, 0.f, 0.f}, 0, 0, 0);

    float mx = -1e30f;
    #pragma unroll
    for (int t = 0; t < 8; ++t)
      #pragma unroll
      for (int r = 0; r < 4; ++r) mx = fmaxf(mx, s[t][r]);
    mx = fmaxf(mx, __shfl_xor(mx, 16));
    mx = fmaxf(mx, __shfl_xor(mx, 32));
    float mn = fmaxf(m_r, mx);
    float al = exp2f(m_r - mn);
    m_r = mn;
    float p[8][4], sm = 0.f;
    #pragma unroll
    for (int t = 0; t < 8; ++t)
      #pragma unroll
      for (int r = 0; r < 4; ++r) {
        p[t][r] = exp2f(s[t][r] - mn);
        sm += p[t][r];
      }
    sm += __shfl_xor(sm, 16);
    sm += __shfl_xor(sm, 32);
    l_r = l_r * al + sm;

    #pragma unroll
    for (int t = 0; t < 8; ++t)
      *(uint2*)&ps[buf][w * 16 + m][t * 16 + quad * 4] =
          make_uint2(pack_rtz(p[t][0], p[t][1]), pack_rtz(p[t][2], p[t][3]));
    if (quad == 0) als[buf][w * 16 + m] = al;

    lds_barrier();   // LDS visibility only; K/V loads stay outstanding

    #pragma unroll
    for (int t = 0; t < 4; ++t) {
      float4 alv = *(const float4*)&als[buf][t * 16 + quad * 4];
      #pragma unroll
      for (int ct = 0; ct < 4; ++ct) {
        o[t][ct][0] *= alv.x; o[t][ct][1] *= alv.y;
        o[t][ct][2] *= alv.z; o[t][ct][3] *= alv.w;
      }
    }

    #pragma unroll
    for (int t = 0; t < 4; ++t) {
      #pragma unroll
      for (int kk = 0; kk < 4; ++kk) {
        bf16x8 pf = *(const bf16x8*)&ps[buf][t * 16 + m][kk * 32 + quad * 8];
        #pragma unroll
        for (int ct = 0; ct < 4; ++ct)
          o[t][ct] = __builtin_amdgcn_mfma_f32_16x16x32_bf16(pf, vB[ct][kk], o[t][ct], 0, 0, 0);
      }
    }
  }

  // share 1/l across waves (O rows span all 64 block queries)
  if (quad == 0) lfin[w * 16 + m] = 1.f / l_r;
  lds_barrier();

  u16* Ob = Onorm + (((size_t)ksl * B_ + b) * N_ + i0) * C_ + w * 64;
  #pragma unroll
  for (int t = 0; t < 4; ++t) {
    float4 lv = *(const float4*)&lfin[t * 16 + quad * 4];
    float linv[4] = {lv.x, lv.y, lv.z, lv.w};
    #pragma unroll
    for (int ct = 0; ct < 4; ++ct)
      #pragma unroll
      for (int r = 0; r < 4; ++r)
        Ob[(size_t)(t * 16 + quad * 4 + r) * C_ + ct * 16 + m] = f2bf(o[t][ct][r] * linv[r]);
  }

  if (quad == 0) {
    size_t mli = ((size_t)ksl * B_ + b) * N_ + i0 + w * 16 + m;
    ml[mli] = m_r;
    ml[(size_t)4 * B_ * N_ + mli] = l_r;
  }
}

// ---------------------------------------------------------------------------
// Fused split-K combine + residual + final 1x1 conv:
//   h'[n,c] = sum_s ws[s]*Onorm_s[n,c] + x[n,c]  (built during LDS staging)
//   out = Wo(hi/lo) * h' + bo  -> f32 (B,C,N)
// grid (N/32, B), block 256.
// ---------------------------------------------------------------------------
__global__ __launch_bounds__(256) void out_mfma(
    const u16* __restrict__ Onorm, const float* __restrict__ ml,
    const u16* __restrict__ xTh,
    const u16* __restrict__ WoH, const u16* __restrict__ WoL,
    const float* __restrict__ bo, float* __restrict__ out)
{
  __shared__ __align__(16) u16 hs[32][270];

  const int tid = threadIdx.x;
  const int lane = tid & 63, w = tid >> 6, m = lane & 15, quad = lane >> 4;
  const int b = blockIdx.y, n0 = blockIdx.x * 32;
  constexpr size_t BN = (size_t)B_ * N_;

  #pragma unroll
  for (int it = 0; it < 4; ++it) {
    int chunk = tid + it * 256;
    int row = chunk >> 5, col = (chunk & 31) * 8;
    size_t nrow = (size_t)b * N_ + n0 + row;

    float mm0 = ml[nrow], mm1 = ml[BN + nrow], mm2 = ml[2 * BN + nrow], mm3 = ml[3 * BN + nrow];
    float M = fmaxf(fmaxf(mm0, mm1), fmaxf(mm2, mm3));
    float ws[4];
    ws[0] = ml[4 * BN + nrow] * exp2f(mm0 - M);
    ws[1] = ml[5 * BN + nrow] * exp2f(mm1 - M);
    ws[2] = ml[6 * BN + nrow] * exp2f(mm2 - M);
    ws[3] = ml[7 * BN + nrow] * exp2f(mm3 - M);
    float inv = 1.f / (ws[0] + ws[1] + ws[2] + ws[3]);
    #pragma unroll
    for (int s = 0; s < 4; ++s) ws[s] *= inv;

    uint4 xv = *(const uint4*)(xTh + nrow * C_ + col);
    u32 xq[4] = {xv.x, xv.y, xv.z, xv.w};
    float acc[8];
    #pragma unroll
    for (int j = 0; j < 4; ++j) {
      acc[2 * j]     = bf2f((u16)(xq[j] & 0xffff));
      acc[2 * j + 1] = bf2f((u16)(xq[j] >> 16));
    }
    #pragma unroll
    for (int s = 0; s < 4; ++s) {
      uint4 ovv = *(const uint4*)(Onorm + (s * BN + nrow) * C_ + col);
      u32 oq[4] = {ovv.x, ovv.y, ovv.z, ovv.w};
      #pragma unroll
      for (int j = 0; j < 4; ++j) {
        acc[2 * j]     += ws[s] * bf2f((u16)(oq[j] & 0xffff));
        acc[2 * j + 1] += ws[s] * bf2f((u16)(oq[j] >> 16));
      }
    }
    uint4 pk;
    pk.x = (u32)f2bf(acc[0]) | ((u32)f2bf(acc[1]) << 16);
    pk.y = (u32)f2bf(acc[2]) | ((u32)f2bf(acc[3]) << 16);
    pk.z = (u32)f2bf(acc[4]) | ((u32)f2bf(acc[5]) << 16);
    pk.w = (u32)f2bf(acc[6]) | ((u32)f2bf(acc[7]) << 16);
    *(uint4*)&hs[row][col] = pk;
  }
  __syncthreads();

  f32x4 o[4][2];
  #pragma unroll
  for (int dt = 0; dt < 4; ++dt)
    #pragma unroll
    for (int nt = 0; nt < 2; ++nt) o[dt][nt] = (f32x4){0.f, 0.f, 0.f, 0.f};

  for (int K = 0; K < 8; ++K) {
    const int ko = K * 32 + quad * 8;
    bf16x8 hf[2];
    #pragma unroll
    for (int nt = 0; nt < 2; ++nt) hf[nt] = *(const bf16x8*)&hs[nt * 16 + m][ko];
    #pragma unroll
    for (int dt = 0; dt < 4; ++dt) {
      bf16x8 whi = *(const bf16x8*)(WoH + (size_t)(64 * w + dt * 16 + m) * C_ + ko);
      bf16x8 wlo = *(const bf16x8*)(WoL + (size_t)(64 * w + dt * 16 + m) * C_ + ko);
      #pragma unroll
      for (int nt = 0; nt < 2; ++nt) {
        o[dt][nt] = __builtin_amdgcn_mfma_f32_16x16x32_bf16(whi, hf[nt], o[dt][nt], 0, 0, 0);
        o[dt][nt] = __builtin_amdgcn_mfma_f32_16x16x32_bf16(wlo, hf[nt], o[dt][nt], 0, 0, 0);
      }
    }
  }

  #pragma unroll
  for (int dt = 0; dt < 4; ++dt)
    #pragma unroll
    for (int r = 0; r < 4; ++r) {
      int d = 64 * w + dt * 16 + quad * 4 + r;
      float bias = bo[d];
      #pragma unroll
      for (int nt = 0; nt < 2; ++nt)
        out[((size_t)b * C_ + d) * N_ + n0 + nt * 16 + m] = o[dt][nt][r] + bias;
    }
}

// ---------------------------------------------------------------------------
extern "C" void kernel_launch(void* const* d_in, const int* in_sizes, int n_in,
                              void* d_out, int out_size, void* d_ws, size_t ws_size,
                              hipStream_t stream)
{
  const float* x  = (const float*)d_in[0];
  const float* Wq = (const float*)d_in[1];
  const float* bq = (const float*)d_in[2];
  const float* Wk = (const float*)d_in[3];
  const float* bk = (const float*)d_in[4];
  const float* Wv = (const float*)d_in[5];
  const float* bv = (const float*)d_in[6];
  const float* Wo = (const float*)d_in[7];
  const float* bo = (const float*)d_in[8];

  // workspace (~53 MB). Onorm ALIASES xTl: xTl is dead after qkv_mfma,
  // Onorm is written only by attn_mfma (stream-ordered after qkv).
  u16* p = (u16*)d_ws;
  u16* qt  = p;  p += (size_t)B_ * N_ * C8_;   // 1 MB
  u16* kt  = p;  p += (size_t)B_ * N_ * C8_;   // 1 MB
  u16* vb  = p;  p += (size_t)B_ * C_ * N_;    // 8 MB
  u16* xTh = p;  p += (size_t)B_ * N_ * C_;    // 8 MB
  u16* WqH = p;  p += 8192;
  u16* WqL = p;  p += 8192;
  u16* WkH = p;  p += 8192;
  u16* WkL = p;  p += 8192;
  u16* WvH = p;  p += 65536;
  u16* WoH = p;  p += 65536;
  u16* WoL = p;  p += 65536;
  float* ml = (float*)p;  p += (size_t)16 * B_ * N_;  // 8*BN floats = 512 KB
  u16* xTl   = p;                               // 8 MB (dead after qkv)
  u16* Onorm = p;                               // 33.5 MB (4,B,N,C) bf16

  float* out = (float*)d_out;

  wsplit<<<576, 256, 0, stream>>>(Wq, Wk, Wv, Wo,
      WqH, WqL, WkH, WkL, WvH, WoH, WoL);
  xprep<<<dim3(N_ / 64, C_ / 64, B_), 256, 0, stream>>>(x, xTh, xTl);
  qkv_mfma<<<dim3(N_ / 32, B_), 256, 0, stream>>>(
      xTh, xTl, WqH, WqL, WkH, WkL, WvH, bq, bk, bv, qt, kt, vb);
  attn_mfma<<<dim3(N_ / 64, 4, B_), 256, 0, stream>>>(qt, kt, vb, Onorm, ml);
  out_mfma<<<dim3(N_ / 32, B_), 256, 0, stream>>>(Onorm, ml, xTh, WoH, WoL, bo, out);
}